// Round 8
// baseline (3097.995 us; speedup 1.0000x reference)
//
#include <hip/hip_runtime.h>

#define T_STEPS 512
#define BATCH   64
#define IN      512
#define HID     1024
#define GDIM    4096

typedef __attribute__((ext_vector_type(8))) short bf16x8_t;
typedef __attribute__((ext_vector_type(4))) float f32x4_t;

__device__ __forceinline__ unsigned short f2bf(float f) {
  union { float f; unsigned int u; } v; v.f = f;
  unsigned int r = v.u + 0x7FFFu + ((v.u >> 16) & 1u);
  return (unsigned short)(r >> 16);
}
__device__ __forceinline__ float bf2f(unsigned short u) {
  union { unsigned int u; float f; } v; v.u = ((unsigned int)u) << 16;
  return v.f;
}
__device__ __forceinline__ float sigmoidf_(float x) {
  return 1.0f / (1.0f + __expf(-x));
}
__device__ __forceinline__ float tanhf_(float x) {
  return 1.0f - 2.0f / (__expf(2.0f * x) + 1.0f);
}

// ---------------- fp32 -> bf16 conversion ----------------
__global__ void k_cvt(const float* __restrict__ src, unsigned short* __restrict__ dst, int n) {
  int i = (blockIdx.x * blockDim.x + threadIdx.x) * 4;
  if (i + 3 < n) {
    float4 f = *(const float4*)(src + i);
    ushort4 o;
    o.x = f2bf(f.x); o.y = f2bf(f.y); o.z = f2bf(f.z); o.w = f2bf(f.w);
    *(ushort4*)(dst + i) = o;
  }
}

__global__ void k_bias(const float* __restrict__ a, const float* __restrict__ b,
                       float* __restrict__ o) {
  int i = blockIdx.x * blockDim.x + threadIdx.x;
  if (i < GDIM) o[i] = a[i] + b[i];
}

// ---------------- persistent fused LSTM (cooperative) ----------------
// 256 blocks x 512 threads: blockIdx = bg*64 + cs. Block owns batches
// [bg*16,+16) x hidden cols [cs*16,+16).
// Waves 0-3: R3-proven recurrence (wave = gate, W_hh slice in AGPR/VGPR).
// Waves 4-7: x-projection producers, gate = w-4. They compute
// xp(t+2) = x(t+2) @ W_ih^T + bias into a 4-slot LDS ring, doing their work
// BEFORE the barriers where rec waves stall (poll / h-load) so it's hidden.
// Handshake (R3-proven + tree): per-wave relaxed-agent RMW on one of 8
// counters (distinct 128B lines, depth 32 each); wave-0-only poll, lane l
// reads counter l&7. No acquire/release anywhere (L2-flush hazard).
__global__ __launch_bounds__(512, 1) void k_lstm_persist(
    const float* __restrict__ x,
    const unsigned short* __restrict__ Wih,
    const unsigned short* __restrict__ Whh,
    const float* __restrict__ bih,
    const float* __restrict__ bhh,
    unsigned short* __restrict__ hbuf0,
    unsigned short* __restrict__ hbuf1,
    float* __restrict__ out,
    float* __restrict__ hT,
    float* __restrict__ cT,
    unsigned int* __restrict__ flags)
{
  __shared__ __align__(16) unsigned short Hlds[16384];  // 16x1024 bf16, XOR-swizzled (2048B rows)
  __shared__ __align__(16) unsigned short XAlds[8192];  // 16x512  bf16, XOR-swizzled (1024B rows)
  __shared__ float Glds[4][16][17];
  __shared__ float Ring[4][4][16][17];                  // [slot][gate][batch][col]

  const int tid = threadIdx.x;
  const int w = tid >> 6, l = tid & 63;
  const int bg = blockIdx.x >> 6;       // batch group 0..3
  const int cs = blockIdx.x & 63;       // hidden-col slice 0..63
  const int b0 = bg * 16, n0 = cs * 16;
  const bool isrec = (w < 4);

  // weight fragments: rec waves use [0..31] from W_hh; xp waves overlay
  // [0..15] with their W_ih slice (register sharing keeps VGPR ~= R3).
  bf16x8_t wfrag[32];
  float bvx = 0.0f;
  if (isrec) {
    const int gc = (w << 10) + n0 + (l & 15);
    const unsigned short* wp = Whh + (size_t)gc * HID + ((l >> 4) * 8);
    #pragma unroll
    for (int ks = 0; ks < 32; ++ks)
      wfrag[ks] = *(const bf16x8_t*)(wp + ks * 32);
  } else {
    const int gx = w - 4;
    const int gcx = (gx << 10) + n0 + (l & 15);
    const unsigned short* wpx = Wih + (size_t)gcx * IN + ((l >> 4) * 8);
    #pragma unroll
    for (int ks = 0; ks < 16; ++ks)
      wfrag[ks] = *(const bf16x8_t*)(wpx + ks * 32);
    bvx = bih[gcx] + bhh[gcx];
  }

  // rec elementwise ids (valid for tid < 256)
  const int eb = tid >> 4, en = tid & 15;
  const size_t ci = (size_t)(b0 + eb) * HID + n0 + en;
  float creg = 0.0f;

  // swizzled LDS addressing
  const int abase  = (l & 15) * 2048 + ((l >> 4) * 16);  // Hlds A-frag
  const int abx    = (l & 15) * 1024 + ((l >> 4) * 16);  // XAlds A-frag
  const int amask  = (l & 7) << 4;
  const int mrow   = (l >> 4) * 4;

  // tree flags: 8 counters per group, 128B apart; depth 32 per step
  unsigned int* const fgrp = flags + bg * 256;
  unsigned int* const fcnt = fgrp + (((cs << 2) + (w & 3)) & 7) * 32;
  const unsigned long long fap = (unsigned long long)(fgrp + (l & 7) * 32);

  // ---- xp helpers (macros keep everything in registers / static idx) ----
#define STAGE_XA(T2) do { \
    int xt = tid - 256; \
    _Pragma("unroll") \
    for (int it = 0; it < 4; ++it) { \
      int c = xt + it * 256;                  /* 0..1023 x 16B chunks */ \
      int row = c >> 6; \
      int j0 = (c & 63) * 8; \
      const float* s_ = x + ((size_t)(T2) * BATCH + b0 + row) * IN + j0; \
      float4 f0 = *(const float4*)(s_); \
      float4 f1 = *(const float4*)(s_ + 4); \
      union { bf16x8_t v; unsigned short s[8]; } u_; \
      u_.s[0]=f2bf(f0.x); u_.s[1]=f2bf(f0.y); u_.s[2]=f2bf(f0.z); u_.s[3]=f2bf(f0.w); \
      u_.s[4]=f2bf(f1.x); u_.s[5]=f2bf(f1.y); u_.s[6]=f2bf(f1.z); u_.s[7]=f2bf(f1.w); \
      int d = c * 16; \
      int sd = d ^ (((d >> 10) & 7) << 4); \
      *(bf16x8_t*)((char*)XAlds + sd) = u_.v; \
    } \
  } while (0)

#define XP_COMPUTE(T2) do { \
    int slot = (T2) & 3; \
    int gx = w - 4; \
    f32x4_t axc = {0.f, 0.f, 0.f, 0.f}; \
    _Pragma("unroll") \
    for (int ks = 0; ks < 16; ++ks) { \
      bf16x8_t a_ = *(const bf16x8_t*)((const char*)XAlds + ((abx + ks * 64) ^ amask)); \
      axc = __builtin_amdgcn_mfma_f32_16x16x32_bf16(a_, wfrag[ks], axc, 0, 0, 0); \
    } \
    Ring[slot][gx][mrow + 0][l & 15] = axc[0] + bvx; \
    Ring[slot][gx][mrow + 1][l & 15] = axc[1] + bvx; \
    Ring[slot][gx][mrow + 2][l & 15] = axc[2] + bvx; \
    Ring[slot][gx][mrow + 3][l & 15] = axc[3] + bvx; \
  } while (0)

  // ---- warm-up: fill ring slots 0 and 1 (rec waves just hit barriers) ----
  if (!isrec) STAGE_XA(0);
  __syncthreads();
  if (!isrec) XP_COMPUTE(0);
  __syncthreads();
  if (!isrec) STAGE_XA(1);
  __syncthreads();
  if (!isrec) XP_COMPUTE(1);
  __syncthreads();

  #pragma unroll 1
  for (int t = 0; t < T_STEPS; ++t) {
    const unsigned short* hc = (t & 1) ? hbuf1 : hbuf0;
    unsigned short*       hn = (t & 1) ? hbuf0 : hbuf1;

    // ---- seg1: xp stage x(t+2) | rec wave0 polls ----
    if (!isrec) {
      if (t + 2 < T_STEPS) STAGE_XA(t + 2);
    } else if (w == 0 && t > 0) {
      const unsigned int target = 32u * (unsigned int)t;
      for (;;) {
        unsigned int v;
        asm volatile("global_load_dword %0, %1, off sc0 sc1"
                     : "=v"(v) : "v"(fap) : "memory");
        asm volatile("s_waitcnt vmcnt(0)" ::: "memory");
        if (__all((int)(v >= target))) break;
        __builtin_amdgcn_s_sleep(1);
      }
    }
    __syncthreads();

    // ---- seg2: rec stage h (32KB, sc-bypass) | xp compute ring[t+2] ----
    if (isrec) {
      const char* hsrc = (const char*)(hc + (size_t)b0 * HID);
      bf16x8_t hv8[8];
      #pragma unroll
      for (int i = 0; i < 8; ++i) {
        unsigned long long ap = (unsigned long long)(hsrc + (size_t)(i * 256 + tid) * 16);
        asm volatile("global_load_dwordx4 %0, %1, off sc0 sc1"
                     : "=v"(hv8[i]) : "v"(ap) : "memory");
      }
      asm volatile("s_waitcnt vmcnt(0)" ::: "memory");
      __builtin_amdgcn_sched_barrier(0);
      #pragma unroll
      for (int i = 0; i < 8; ++i) {
        int d = (i * 256 + tid) * 16;
        int sd = d ^ (((d >> 11) & 7) << 4);
        *(bf16x8_t*)((char*)Hlds + sd) = hv8[i];
      }
    } else {
      if (t + 2 < T_STEPS) XP_COMPUTE(t + 2);
    }
    __syncthreads();

    // ---- seg3: rec MFMA h @ W_hh^T ----
    if (isrec) {
      f32x4_t ac0 = {0,0,0,0}, ac1 = {0,0,0,0}, ac2 = {0,0,0,0}, ac3 = {0,0,0,0};
      #pragma unroll
      for (int ks = 0; ks < 32; ks += 4) {
        bf16x8_t a0 = *(const bf16x8_t*)((const char*)Hlds + ((abase + (ks+0)*64) ^ amask));
        bf16x8_t a1 = *(const bf16x8_t*)((const char*)Hlds + ((abase + (ks+1)*64) ^ amask));
        bf16x8_t a2 = *(const bf16x8_t*)((const char*)Hlds + ((abase + (ks+2)*64) ^ amask));
        bf16x8_t a3 = *(const bf16x8_t*)((const char*)Hlds + ((abase + (ks+3)*64) ^ amask));
        ac0 = __builtin_amdgcn_mfma_f32_16x16x32_bf16(a0, wfrag[ks+0], ac0, 0, 0, 0);
        ac1 = __builtin_amdgcn_mfma_f32_16x16x32_bf16(a1, wfrag[ks+1], ac1, 0, 0, 0);
        ac2 = __builtin_amdgcn_mfma_f32_16x16x32_bf16(a2, wfrag[ks+2], ac2, 0, 0, 0);
        ac3 = __builtin_amdgcn_mfma_f32_16x16x32_bf16(a3, wfrag[ks+3], ac3, 0, 0, 0);
      }
      f32x4_t s = ac0 + ac1 + ac2 + ac3;
      Glds[w][mrow + 0][l & 15] = s[0];
      Glds[w][mrow + 1][l & 15] = s[1];
      Glds[w][mrow + 2][l & 15] = s[2];
      Glds[w][mrow + 3][l & 15] = s[3];
    }
    __syncthreads();

    // ---- epilogue: rec gates + state + publish ----
    if (isrec) {
      const int rs = t & 3;
      float pre0 = Glds[0][eb][en] + Ring[rs][0][eb][en];
      float pre1 = Glds[1][eb][en] + Ring[rs][1][eb][en];
      float pre2 = Glds[2][eb][en] + Ring[rs][2][eb][en];
      float pre3 = Glds[3][eb][en] + Ring[rs][3][eb][en];
      float ig = sigmoidf_(pre0);
      float fg = sigmoidf_(pre1);
      float gg = tanhf_(pre2);
      float og = sigmoidf_(pre3);
      creg = fg * creg + ig * gg;
      float hv = og * tanhf_(creg);

      if (t == T_STEPS - 1) {
        out[((size_t)t * BATCH + b0 + eb) * HID + n0 + en] = hv;
        hT[ci] = hv;
        cT[ci] = creg;
      } else {
        // publish h(t): packed bf16 pairs, relaxed-agent stores
        unsigned short mybf = f2bf(hv);
        unsigned short pbf = (unsigned short)(unsigned int)
            __shfl_xor((int)(unsigned int)mybf, 1, 64);
        if ((l & 1) == 0) {
          unsigned int pk = ((unsigned int)mybf) | (((unsigned int)pbf) << 16);
          __hip_atomic_store((unsigned int*)(hn + ci), pk,
                             __ATOMIC_RELAXED, __HIP_MEMORY_SCOPE_AGENT);
        }
        // wave-local drain, then this wave's tree-counter increment
        asm volatile("s_waitcnt vmcnt(0)" ::: "memory");
        if (l == 0)
          (void)__hip_atomic_fetch_add(fcnt, 1u, __ATOMIC_RELAXED,
                                       __HIP_MEMORY_SCOPE_AGENT);
        // out store AFTER publish: off the critical drain path
        out[((size_t)t * BATCH + b0 + eb) * HID + n0 + en] = hv;
      }
    }
  }
#undef STAGE_XA
#undef XP_COMPUTE
}

// ---------------- fallback per-timestep kernel (small workspace) ----------------
__global__ __launch_bounds__(256) void k_step_fused(
    const unsigned short* __restrict__ hprev,
    unsigned short* __restrict__ hnext,
    float* __restrict__ cstate,
    const unsigned short* __restrict__ Whh,
    const unsigned short* __restrict__ Wih,
    const float* __restrict__ x,
    const float* __restrict__ bias,
    float* __restrict__ out,
    float* __restrict__ hT, float* __restrict__ cT,
    int t, int is_last)
{
  const int RS = 1560;
  const int XB = 1032;
  __shared__ unsigned short Hlds[16 * RS];
  __shared__ float Glds[4][16][17];
  const int tid = threadIdx.x;
  const int w = tid >> 6, l = tid & 63;
  const int bg = blockIdx.x >> 6, hs = blockIdx.x & 63;
  const int b0 = bg * 16, n0 = hs * 16;

  #pragma unroll
  for (int it = 0; it < 8; ++it) {
    int chunk = tid + it * 256;
    int row = chunk >> 7;
    int cc  = (chunk & 127) * 8;
    *(bf16x8_t*)&Hlds[row * RS + cc] =
        *(const bf16x8_t*)(hprev + (size_t)(b0 + row) * HID + cc);
  }
  #pragma unroll
  for (int it = 0; it < 4; ++it) {
    int chunk = tid + it * 256;
    int row = chunk >> 6;
    int cc  = (chunk & 63) * 8;
    const float* src = x + ((size_t)t * BATCH + b0 + row) * IN + cc;
    float4 f0 = *(const float4*)(src);
    float4 f1 = *(const float4*)(src + 4);
    union { bf16x8_t v; unsigned short s[8]; } u;
    u.s[0]=f2bf(f0.x); u.s[1]=f2bf(f0.y); u.s[2]=f2bf(f0.z); u.s[3]=f2bf(f0.w);
    u.s[4]=f2bf(f1.x); u.s[5]=f2bf(f1.y); u.s[6]=f2bf(f1.z); u.s[7]=f2bf(f1.w);
    *(bf16x8_t*)&Hlds[row * RS + XB + cc] = u.v;
  }
  __syncthreads();

  f32x4_t acc = {0.f, 0.f, 0.f, 0.f};
  const int gcol = (w << 10) + n0 + (l & 15);
  const unsigned short* wp = Whh + (size_t)gcol * HID + ((l >> 4) * 8);
  const unsigned short* ap = &Hlds[(l & 15) * RS + ((l >> 4) * 8)];
  #pragma unroll 4
  for (int ks = 0; ks < 32; ++ks) {
    bf16x8_t a = *(const bf16x8_t*)(ap);
    bf16x8_t b = *(const bf16x8_t*)(wp);
    acc = __builtin_amdgcn_mfma_f32_16x16x32_bf16(a, b, acc, 0, 0, 0);
    ap += 32; wp += 32;
  }
  const unsigned short* wpx = Wih + (size_t)gcol * IN + ((l >> 4) * 8);
  const unsigned short* apx = &Hlds[(l & 15) * RS + XB + ((l >> 4) * 8)];
  #pragma unroll 4
  for (int ks = 0; ks < 16; ++ks) {
    bf16x8_t a = *(const bf16x8_t*)(apx);
    bf16x8_t b = *(const bf16x8_t*)(wpx);
    acc = __builtin_amdgcn_mfma_f32_16x16x32_bf16(a, b, acc, 0, 0, 0);
    apx += 32; wpx += 32;
  }

  {
    int r0 = (l >> 4) * 4, cc = l & 15;
    Glds[w][r0 + 0][cc] = acc[0];
    Glds[w][r0 + 1][cc] = acc[1];
    Glds[w][r0 + 2][cc] = acc[2];
    Glds[w][r0 + 3][cc] = acc[3];
  }
  __syncthreads();

  int b = tid >> 4, n = tid & 15;
  float pre[4];
  #pragma unroll
  for (int g = 0; g < 4; ++g)
    pre[g] = Glds[g][b][n] + bias[(g << 10) + n0 + n];
  float ig = sigmoidf_(pre[0]);
  float fg = sigmoidf_(pre[1]);
  float gg = tanhf_(pre[2]);
  float og = sigmoidf_(pre[3]);
  size_t ci = (size_t)(b0 + b) * HID + n0 + n;
  float cn = fg * cstate[ci] + ig * gg;
  float hv = og * tanhf_(cn);
  cstate[ci] = cn;
  out[((size_t)t * BATCH + b0 + b) * HID + n0 + n] = hv;
  hnext[ci] = f2bf(hv);
  if (is_last) { hT[ci] = hv; cT[ci] = cn; }
}

// ---------------- host launch ----------------
extern "C" void kernel_launch(void* const* d_in, const int* in_sizes, int n_in,
                              void* d_out, int out_size, void* d_ws, size_t ws_size,
                              hipStream_t stream) {
  const float* x    = (const float*)d_in[0];
  const float* Wihf = (const float*)d_in[1];
  const float* bih  = (const float*)d_in[2];
  const float* Whhf = (const float*)d_in[3];
  const float* bhh  = (const float*)d_in[4];
  float* out = (float*)d_out;

  char* ws = (char*)d_ws;
  size_t off = 0;
  auto take = [&](size_t bytes) {
    char* p = ws + off;
    off = (off + bytes + 255) & ~(size_t)255;
    return p;
  };
  unsigned short* wih_b = (unsigned short*)take((size_t)GDIM * IN * 2);   // 4 MB
  unsigned short* whh_b = (unsigned short*)take((size_t)GDIM * HID * 2);  // 8 MB
  float*          bias  = (float*)take((size_t)GDIM * 4);
  unsigned short* h0    = (unsigned short*)take((size_t)BATCH * HID * 2);
  unsigned short* h1    = (unsigned short*)take((size_t)BATCH * HID * 2);
  float*          cbuf  = (float*)take((size_t)BATCH * HID * 4);
  unsigned int*   flags = (unsigned int*)take((size_t)4 * 256 * 4);       // 4 groups x 8 ctrs x 128B
  size_t full_need = off;
  const int primary = (ws_size >= full_need) ? 1 : 0;
  (void)in_sizes; (void)n_in; (void)out_size;

  k_cvt<<<(GDIM * IN / 4 + 255) / 256, 256, 0, stream>>>(Wihf, wih_b, GDIM * IN);
  k_cvt<<<(GDIM * HID / 4 + 255) / 256, 256, 0, stream>>>(Whhf, whh_b, GDIM * HID);
  (void)hipMemsetAsync(h0, 0, (size_t)BATCH * HID * 2, stream);

  float* hT = out + (size_t)T_STEPS * BATCH * HID;
  float* cT = hT + (size_t)BATCH * HID;

  if (primary) {
    (void)hipMemsetAsync(flags, 0, (size_t)4 * 256 * 4, stream);
    void* p_x = (void*)x;       void* p_wih = (void*)wih_b;
    void* p_whh = (void*)whh_b; void* p_bih = (void*)bih;
    void* p_bhh = (void*)bhh;   void* p_h0 = (void*)h0;
    void* p_h1 = (void*)h1;     void* p_out = (void*)out;
    void* p_hT = (void*)hT;     void* p_cT = (void*)cT;
    void* p_fl = (void*)flags;
    void* args[11] = {&p_x, &p_wih, &p_whh, &p_bih, &p_bhh, &p_h0, &p_h1,
                      &p_out, &p_hT, &p_cT, &p_fl};
    (void)hipLaunchCooperativeKernel((const void*)k_lstm_persist,
                                     dim3(256), dim3(512), args, 0, stream);
  } else {
    k_bias<<<(GDIM + 255) / 256, 256, 0, stream>>>(bih, bhh, bias);
    (void)hipMemsetAsync(cbuf, 0, (size_t)BATCH * HID * 4, stream);
    unsigned short* hp = h0;
    unsigned short* hn = h1;
    for (int t = 0; t < T_STEPS; ++t) {
      int last = (t == T_STEPS - 1) ? 1 : 0;
      k_step_fused<<<256, 256, 0, stream>>>(hp, hn, cbuf, whh_b, wih_b, x, bias,
                                            out, hT, cT, t, last);
      unsigned short* tmp = hp; hp = hn; hn = tmp;
    }
  }
}

// Round 11
// 2040.641 us; speedup vs baseline: 1.5181x; 1.5181x over previous
//
#include <hip/hip_runtime.h>

#define T_STEPS 512
#define BATCH   64
#define IN      512
#define HID     1024
#define GDIM    4096
#define MROWS   (T_STEPS * BATCH)

typedef __attribute__((ext_vector_type(8))) short bf16x8_t;
typedef __attribute__((ext_vector_type(4))) float f32x4_t;

__device__ __forceinline__ unsigned short f2bf(float f) {
  union { float f; unsigned int u; } v; v.f = f;
  unsigned int r = v.u + 0x7FFFu + ((v.u >> 16) & 1u);
  return (unsigned short)(r >> 16);
}
__device__ __forceinline__ float bf2f(unsigned short u) {
  union { unsigned int u; float f; } v; v.u = ((unsigned int)u) << 16;
  return v.f;
}
__device__ __forceinline__ float sigmoidf_(float x) {
  return 1.0f / (1.0f + __expf(-x));
}
__device__ __forceinline__ float tanhf_(float x) {
  return 1.0f - 2.0f / (__expf(2.0f * x) + 1.0f);
}
__device__ __forceinline__ f32x4_t MFMA_(bf16x8_t a, bf16x8_t b, f32x4_t c) {
  return __builtin_amdgcn_mfma_f32_16x16x32_bf16(a, b, c, 0, 0, 0);
}

// ---------------- fp32 -> bf16 conversion ----------------
__global__ void k_cvt(const float* __restrict__ src, unsigned short* __restrict__ dst, int n) {
  int i = (blockIdx.x * blockDim.x + threadIdx.x) * 4;
  if (i + 3 < n) {
    float4 f = *(const float4*)(src + i);
    ushort4 o;
    o.x = f2bf(f.x); o.y = f2bf(f.y); o.z = f2bf(f.z); o.w = f2bf(f.w);
    *(ushort4*)(dst + i) = o;
  }
}

__global__ void k_bias(const float* __restrict__ a, const float* __restrict__ b,
                       float* __restrict__ o) {
  int i = blockIdx.x * blockDim.x + threadIdx.x;
  if (i < GDIM) o[i] = a[i] + b[i];
}

// ---------------- x_proj GEMM: [32768 x 512] @ W_ih^T -> bf16 [32768 x 4096] ----------------
__global__ __launch_bounds__(256) void k_xproj(
    const float* __restrict__ x,
    const unsigned short* __restrict__ Wih,
    const float* __restrict__ bias,
    unsigned short* __restrict__ xproj)
{
  const int AP = 40;
  __shared__ unsigned short Alds[128 * AP];
  __shared__ unsigned short Blds[128 * AP];
  const int tid = threadIdx.x;
  const int w = tid >> 6, l = tid & 63;
  const int m0 = blockIdx.y * 128, n0 = blockIdx.x * 128;
  const int wm = (w >> 1) * 64, wn = (w & 1) * 64;
  f32x4_t acc[4][4] = {};

  for (int k0 = 0; k0 < IN; k0 += 32) {
    #pragma unroll
    for (int it = 0; it < 2; ++it) {
      int chunk = tid + it * 256;
      int row = chunk >> 2;
      int kc  = (chunk & 3) * 8;
      const float* src = x + (size_t)(m0 + row) * IN + k0 + kc;
      float4 f0 = *(const float4*)(src);
      float4 f1 = *(const float4*)(src + 4);
      union { bf16x8_t v; unsigned short s[8]; } u;
      u.s[0]=f2bf(f0.x); u.s[1]=f2bf(f0.y); u.s[2]=f2bf(f0.z); u.s[3]=f2bf(f0.w);
      u.s[4]=f2bf(f1.x); u.s[5]=f2bf(f1.y); u.s[6]=f2bf(f1.z); u.s[7]=f2bf(f1.w);
      *(bf16x8_t*)&Alds[row * AP + kc] = u.v;
    }
    #pragma unroll
    for (int it = 0; it < 2; ++it) {
      int chunk = tid + it * 256;
      int row = chunk >> 2;
      int kc  = (chunk & 3) * 8;
      *(bf16x8_t*)&Blds[row * AP + kc] =
          *(const bf16x8_t*)(Wih + (size_t)(n0 + row) * IN + k0 + kc);
    }
    __syncthreads();
    bf16x8_t a[4], b[4];
    #pragma unroll
    for (int i = 0; i < 4; ++i)
      a[i] = *(const bf16x8_t*)&Alds[(wm + i * 16 + (l & 15)) * AP + ((l >> 4) * 8)];
    #pragma unroll
    for (int i = 0; i < 4; ++i)
      b[i] = *(const bf16x8_t*)&Blds[(wn + i * 16 + (l & 15)) * AP + ((l >> 4) * 8)];
    #pragma unroll
    for (int mi = 0; mi < 4; ++mi) {
      #pragma unroll
      for (int ni = 0; ni < 4; ++ni)
        acc[mi][ni] = __builtin_amdgcn_mfma_f32_16x16x32_bf16(a[mi], b[ni], acc[mi][ni], 0, 0, 0);
    }
    __syncthreads();
  }
  #pragma unroll
  for (int ni = 0; ni < 4; ++ni) {
    int col = n0 + wn + ni * 16 + (l & 15);
    float bv = bias[col];
    #pragma unroll
    for (int mi = 0; mi < 4; ++mi) {
      int rbase = m0 + wm + mi * 16 + (l >> 4) * 4;
      #pragma unroll
      for (int r = 0; r < 4; ++r)
        xproj[(size_t)(rbase + r) * GDIM + col] = f2bf(acc[mi][ni][r] + bv);
    }
  }
}

// ---------------- persistent recurrence kernel (cooperative) ----------------
// R3-proven handshake, 8-group partition. 256 blocks x 256 threads:
// blockIdx = grp*32 + slot. Group grp owns batches [grp*8,+8); block owns
// hidden cols [slot*32,+32) x 4 gates. Wave = gate, 2 col-tiles of 16,
// 64 W_hh frags resident in AGPRs. MFMA M=16 with batch rows 8..15 zero-
// padded in LDS (written once, never touched again). All cross-block traffic
// uses relaxed-agent atomics / sc0 sc1 (coherence point; NO acquire/release).
// Handshake per group: per-step monotonic slot counter bar[grp*512+t];
// producers: per-thread vmcnt(0) drain -> __syncthreads -> tid0 fetch_add;
// consumer: tid0-only single-word poll (the R3-measured minimum poll cost).
__global__ __launch_bounds__(256, 1) void k_lstm_persist(
    const unsigned short* __restrict__ xproj,
    const unsigned short* __restrict__ Whh,
    unsigned short* __restrict__ hbuf0,
    unsigned short* __restrict__ hbuf1,
    float* __restrict__ out,
    float* __restrict__ hT,
    float* __restrict__ cT,
    unsigned int* __restrict__ bar)
{
  __shared__ __align__(16) unsigned short Hlds[16384];  // 16 x 1024 bf16; rows 8..15 stay zero
  __shared__ float Glds[4][8][33];

  const int tid = threadIdx.x;
  const int w = tid >> 6, l = tid & 63;
  const int grp  = blockIdx.x >> 5;     // batch group 0..7 (8 batches each)
  const int slot = blockIdx.x & 31;     // col slice 0..31 (32 cols each)
  const int b0 = grp * 8, n0 = slot * 32;

  // zero H tile once (pad rows 8..15 remain zero forever)
  {
    bf16x8_t zv = {0, 0, 0, 0, 0, 0, 0, 0};
    #pragma unroll
    for (int i = 0; i < 8; ++i)
      *(bf16x8_t*)((char*)Hlds + (size_t)(i * 256 + tid) * 16) = zv;
  }
  __syncthreads();

  // --- W_hh fragments: gate w, col-tiles [n0,n0+16) and [n0+16,n0+32) ---
  bf16x8_t wf[64];
  {
    const unsigned short* wp0 =
        Whh + (size_t)((w << 10) + n0 + (l & 15)) * HID + ((l >> 4) * 8);
    const unsigned short* wp1 = wp0 + (size_t)16 * HID;
    #pragma unroll
    for (int ks = 0; ks < 32; ++ks) {
      wf[ks]      = *(const bf16x8_t*)(wp0 + ks * 32);
      wf[32 + ks] = *(const bf16x8_t*)(wp1 + ks * 32);
    }
  }

  // elementwise ids: 256 threads <-> 8 batches x 32 cols
  const int eb = tid >> 5, en = tid & 31;
  const size_t ci = (size_t)(b0 + eb) * HID + n0 + en;
  float creg = 0.0f;

  // swizzled LDS A-frag addressing (2048B rows)
  const int abase = (l & 15) * 2048 + ((l >> 4) * 16);
  const int amask = (l & 7) << 4;

  unsigned int* const fgrp = bar + grp * 512;   // one word per step, per group

  #pragma unroll 1
  for (int t = 0; t < T_STEPS; ++t) {
    const unsigned short* hc = (t & 1) ? hbuf1 : hbuf0;
    unsigned short*       hn = (t & 1) ? hbuf0 : hbuf1;

    // xproj gate values: plain cached loads issued BEFORE the poll
    const unsigned short* xpp = xproj + ((size_t)t * BATCH + b0 + eb) * GDIM + n0 + en;
    unsigned short x0 = xpp[0], x1 = xpp[1024], x2 = xpp[2048], x3 = xpp[3072];
    asm volatile("" ::: "memory");

    // R3-proven poll: tid0 only, single word, then barrier release
    if (t > 0) {
      if (tid == 0) {
        const unsigned int* f = fgrp + (t - 1);
        while (__hip_atomic_load(f, __ATOMIC_RELAXED, __HIP_MEMORY_SCOPE_AGENT) < 32u)
          __builtin_amdgcn_s_sleep(1);
      }
      __syncthreads();
    }

    // stage h[grp] slice: 8 rows x 1024 bf16 = 16KB, sc0 sc1 (coherence point)
    {
      const char* hsrc = (const char*)(hc + (size_t)b0 * HID);
      bf16x8_t hv[4];
      #pragma unroll
      for (int i = 0; i < 4; ++i) {
        unsigned long long ap = (unsigned long long)(hsrc + (size_t)(i * 256 + tid) * 16);
        asm volatile("global_load_dwordx4 %0, %1, off sc0 sc1"
                     : "=v"(hv[i]) : "v"(ap) : "memory");
      }
      asm volatile("s_waitcnt vmcnt(0)" ::: "memory");
      __builtin_amdgcn_sched_barrier(0);
      #pragma unroll
      for (int i = 0; i < 4; ++i) {
        int d = (i * 256 + tid) * 16;               // bytes 0..16383 = rows 0..7
        int sd = d ^ (((d >> 11) & 7) << 4);
        *(bf16x8_t*)((char*)Hlds + sd) = hv[i];
      }
    }
    __syncthreads();

    // MFMA: 32 K-steps x 2 col-tiles (A rows 8..15 are zeros)
    f32x4_t ac0 = {0,0,0,0}, ac1 = {0,0,0,0}, ac2 = {0,0,0,0}, ac3 = {0,0,0,0};
    #pragma unroll
    for (int ks = 0; ks < 32; ks += 2) {
      bf16x8_t a0 = *(const bf16x8_t*)((const char*)Hlds + ((abase + (ks+0)*64) ^ amask));
      bf16x8_t a1 = *(const bf16x8_t*)((const char*)Hlds + ((abase + (ks+1)*64) ^ amask));
      ac0 = MFMA_(a0, wf[ks],          ac0);
      ac1 = MFMA_(a0, wf[32 + ks],     ac1);
      ac2 = MFMA_(a1, wf[ks + 1],      ac2);
      ac3 = MFMA_(a1, wf[32 + ks + 1], ac3);
    }
    f32x4_t s0 = ac0 + ac2;   // cols n0+0..15
    f32x4_t s1 = ac1 + ac3;   // cols n0+16..31

    // gate tile to LDS: D row=(l>>4)*4+j; keep rows 0..7
    if ((l >> 4) < 2) {
      int r0 = (l >> 4) * 4, cc = l & 15;
      #pragma unroll
      for (int j = 0; j < 4; ++j) {
        Glds[w][r0 + j][cc]      = s0[j];
        Glds[w][r0 + j][16 + cc] = s1[j];
      }
    }
    __syncthreads();

    float pre0 = Glds[0][eb][en] + bf2f(x0);
    float pre1 = Glds[1][eb][en] + bf2f(x1);
    float pre2 = Glds[2][eb][en] + bf2f(x2);
    float pre3 = Glds[3][eb][en] + bf2f(x3);
    float ig = sigmoidf_(pre0);
    float fg = sigmoidf_(pre1);
    float gg = tanhf_(pre2);
    float og = sigmoidf_(pre3);
    creg = fg * creg + ig * gg;
    float hv = og * tanhf_(creg);

    if (t == T_STEPS - 1) {
      out[((size_t)t * BATCH + b0 + eb) * HID + n0 + en] = hv;
      hT[ci] = hv;
      cT[ci] = creg;
    } else {
      // publish h(t): packed bf16 pairs, relaxed-agent stores
      unsigned short mybf = f2bf(hv);
      unsigned short pbf = (unsigned short)(unsigned int)
          __shfl_xor((int)(unsigned int)mybf, 1, 64);
      if ((l & 1) == 0) {
        unsigned int pk = ((unsigned int)mybf) | (((unsigned int)pbf) << 16);
        __hip_atomic_store((unsigned int*)(hn + ci), pk,
                           __ATOMIC_RELAXED, __HIP_MEMORY_SCOPE_AGENT);
      }
      // drain h-stores only, then the single per-block RMW (R3-proven)
      asm volatile("s_waitcnt vmcnt(0)" ::: "memory");
      __syncthreads();
      if (tid == 0)
        (void)__hip_atomic_fetch_add(fgrp + t, 1u,
                                     __ATOMIC_RELAXED, __HIP_MEMORY_SCOPE_AGENT);
      // out store AFTER the flag: off the critical drain path
      out[((size_t)t * BATCH + b0 + eb) * HID + n0 + en] = hv;
    }
  }
}

// ---------------- fallback per-timestep kernel (small workspace) ----------------
__global__ __launch_bounds__(256) void k_step_fused(
    const unsigned short* __restrict__ hprev,
    unsigned short* __restrict__ hnext,
    float* __restrict__ cstate,
    const unsigned short* __restrict__ Whh,
    const unsigned short* __restrict__ Wih,
    const float* __restrict__ x,
    const float* __restrict__ bias,
    float* __restrict__ out,
    float* __restrict__ hT, float* __restrict__ cT,
    int t, int is_last)
{
  const int RS = 1560;
  const int XB = 1032;
  __shared__ unsigned short Hlds[16 * RS];
  __shared__ float Glds[4][16][17];
  const int tid = threadIdx.x;
  const int w = tid >> 6, l = tid & 63;
  const int bg = blockIdx.x >> 6, hs = blockIdx.x & 63;
  const int b0 = bg * 16, n0 = hs * 16;

  #pragma unroll
  for (int it = 0; it < 8; ++it) {
    int chunk = tid + it * 256;
    int row = chunk >> 7;
    int cc  = (chunk & 127) * 8;
    *(bf16x8_t*)&Hlds[row * RS + cc] =
        *(const bf16x8_t*)(hprev + (size_t)(b0 + row) * HID + cc);
  }
  #pragma unroll
  for (int it = 0; it < 4; ++it) {
    int chunk = tid + it * 256;
    int row = chunk >> 6;
    int cc  = (chunk & 63) * 8;
    const float* src = x + ((size_t)t * BATCH + b0 + row) * IN + cc;
    float4 f0 = *(const float4*)(src);
    float4 f1 = *(const float4*)(src + 4);
    union { bf16x8_t v; unsigned short s[8]; } u;
    u.s[0]=f2bf(f0.x); u.s[1]=f2bf(f0.y); u.s[2]=f2bf(f0.z); u.s[3]=f2bf(f0.w);
    u.s[4]=f2bf(f1.x); u.s[5]=f2bf(f1.y); u.s[6]=f2bf(f1.z); u.s[7]=f2bf(f1.w);
    *(bf16x8_t*)&Hlds[row * RS + XB + cc] = u.v;
  }
  __syncthreads();

  f32x4_t acc = {0.f, 0.f, 0.f, 0.f};
  const int gcol = (w << 10) + n0 + (l & 15);
  const unsigned short* wp = Whh + (size_t)gcol * HID + ((l >> 4) * 8);
  const unsigned short* ap = &Hlds[(l & 15) * RS + ((l >> 4) * 8)];
  #pragma unroll 4
  for (int ks = 0; ks < 32; ++ks) {
    bf16x8_t a = *(const bf16x8_t*)(ap);
    bf16x8_t b = *(const bf16x8_t*)(wp);
    acc = __builtin_amdgcn_mfma_f32_16x16x32_bf16(a, b, acc, 0, 0, 0);
    ap += 32; wp += 32;
  }
  const unsigned short* wpx = Wih + (size_t)gcol * IN + ((l >> 4) * 8);
  const unsigned short* apx = &Hlds[(l & 15) * RS + XB + ((l >> 4) * 8)];
  #pragma unroll 4
  for (int ks = 0; ks < 16; ++ks) {
    bf16x8_t a = *(const bf16x8_t*)(apx);
    bf16x8_t b = *(const bf16x8_t*)(wpx);
    acc = __builtin_amdgcn_mfma_f32_16x16x32_bf16(a, b, acc, 0, 0, 0);
    apx += 32; wpx += 32;
  }

  {
    int r0 = (l >> 4) * 4, cc = l & 15;
    Glds[w][r0 + 0][cc] = acc[0];
    Glds[w][r0 + 1][cc] = acc[1];
    Glds[w][r0 + 2][cc] = acc[2];
    Glds[w][r0 + 3][cc] = acc[3];
  }
  __syncthreads();

  int b = tid >> 4, n = tid & 15;
  float pre[4];
  #pragma unroll
  for (int g = 0; g < 4; ++g)
    pre[g] = Glds[g][b][n] + bias[(g << 10) + n0 + n];
  float ig = sigmoidf_(pre[0]);
  float fg = sigmoidf_(pre[1]);
  float gg = tanhf_(pre[2]);
  float og = sigmoidf_(pre[3]);
  size_t ci = (size_t)(b0 + b) * HID + n0 + n;
  float cn = fg * cstate[ci] + ig * gg;
  float hv = og * tanhf_(cn);
  cstate[ci] = cn;
  out[((size_t)t * BATCH + b0 + b) * HID + n0 + n] = hv;
  hnext[ci] = f2bf(hv);
  if (is_last) { hT[ci] = hv; cT[ci] = cn; }
}

// ---------------- host launch ----------------
extern "C" void kernel_launch(void* const* d_in, const int* in_sizes, int n_in,
                              void* d_out, int out_size, void* d_ws, size_t ws_size,
                              hipStream_t stream) {
  const float* x    = (const float*)d_in[0];
  const float* Wihf = (const float*)d_in[1];
  const float* bih  = (const float*)d_in[2];
  const float* Whhf = (const float*)d_in[3];
  const float* bhh  = (const float*)d_in[4];
  float* out = (float*)d_out;

  char* ws = (char*)d_ws;
  size_t off = 0;
  auto take = [&](size_t bytes) {
    char* p = ws + off;
    off = (off + bytes + 255) & ~(size_t)255;
    return p;
  };
  unsigned short* wih_b = (unsigned short*)take((size_t)GDIM * IN * 2);   // 4 MB
  unsigned short* whh_b = (unsigned short*)take((size_t)GDIM * HID * 2);  // 8 MB
  float*          bias  = (float*)take((size_t)GDIM * 4);
  unsigned short* h0    = (unsigned short*)take((size_t)BATCH * HID * 2);
  unsigned short* h1    = (unsigned short*)take((size_t)BATCH * HID * 2);
  float*          cbuf  = (float*)take((size_t)BATCH * HID * 4);
  unsigned int*   bar   = (unsigned int*)take((size_t)8 * 512 * 4);       // [grp][t]
  unsigned short* xproj = (unsigned short*)take((size_t)MROWS * GDIM * 2); // 256 MB
  size_t full_need = off;
  const int primary = (ws_size >= full_need) ? 1 : 0;
  (void)in_sizes; (void)n_in; (void)out_size;

  k_cvt<<<(GDIM * IN / 4 + 255) / 256, 256, 0, stream>>>(Wihf, wih_b, GDIM * IN);
  k_cvt<<<(GDIM * HID / 4 + 255) / 256, 256, 0, stream>>>(Whhf, whh_b, GDIM * HID);
  k_bias<<<(GDIM + 255) / 256, 256, 0, stream>>>(bih, bhh, bias);
  (void)hipMemsetAsync(h0, 0, (size_t)BATCH * HID * 2, stream);

  float* hT = out + (size_t)T_STEPS * BATCH * HID;
  float* cT = hT + (size_t)BATCH * HID;

  if (primary) {
    (void)hipMemsetAsync(bar, 0, (size_t)8 * 512 * 4, stream);
    k_xproj<<<dim3(GDIM / 128, MROWS / 128), 256, 0, stream>>>(x, wih_b, bias, xproj);
    void* p_xproj = (void*)xproj; void* p_whh = (void*)whh_b;
    void* p_h0 = (void*)h0;       void* p_h1 = (void*)h1;
    void* p_out = (void*)out;     void* p_hT = (void*)hT;
    void* p_cT = (void*)cT;       void* p_fl = (void*)bar;
    void* args[8] = {&p_xproj, &p_whh, &p_h0, &p_h1, &p_out, &p_hT, &p_cT, &p_fl};
    hipError_t err = hipLaunchCooperativeKernel((const void*)k_lstm_persist,
                                                dim3(256), dim3(256), args, 0, stream);
    if (err == hipSuccess) return;
    // fall through to per-step fallback if the cooperative launch is rejected
  }

  (void)hipMemsetAsync(cbuf, 0, (size_t)BATCH * HID * 4, stream);
  unsigned short* hp = h0;
  unsigned short* hn = h1;
  for (int t = 0; t < T_STEPS; ++t) {
    int last = (t == T_STEPS - 1) ? 1 : 0;
    k_step_fused<<<256, 256, 0, stream>>>(hp, hn, cbuf, whh_b, wih_b, x, bias,
                                          out, hT, cT, t, last);
    unsigned short* tmp = hp; hp = hn; hn = tmp;
  }
}